// Round 7
// baseline (81.034 us; speedup 1.0000x reference)
//
#include <hip/hip_runtime.h>

// Channelwise Sorensen-Dice over (1,3,96,256,256) fp32; each channel is a
// contiguous 6,291,456-float block. Per-channel sum(x*t), sum(x*x), sum(t*t);
// loss = sum_c -2*num/max(den,eps).
//
// R7: fuse the finalize into stage-1 via the threadfence-ticket pattern
// (last-arriving block reduces the 9x512 partials and writes the loss).
// Saves the dependent second kernel launch; the only stream ops are a
// 4-byte memset (ticket counter) + one kernel. Stage-1 streaming is kept
// from R5 (94% of the m13 per-CU request-rate ceiling; R6's deeper
// pipeline was neutral, confirming request-rate-bound).
#define NCH 3
#define PER_CH 6291456
#define THREADS 256
#define WPB 4                       // waves per block
#define GRIDX 512                   // blocks per channel
#define TOTAL_BLOCKS (GRIDX * NCH)  // 1536
#define NWX (GRIDX * WPB)           // 2048 waves per channel
#define CHUNK 512                   // floats per array per chunk (2 KB)
#define CHUNKS_PER_WAVE 6           // PER_CH / CHUNK / NWX == 6 exactly
#define EPS 1e-6f

__device__ __forceinline__ void gload16(const float* g, float* l) {
    // dwordx4 direct global->LDS: lane i's 16B land at l + i*16.
    __builtin_amdgcn_global_load_lds(
        (__attribute__((address_space(1))) void*)g,
        (__attribute__((address_space(3))) void*)l,
        16, 0, 0);
}

// d_ws layout: partial[9*GRIDX] floats (row r = sum kind, col = blockIdx.x),
// then unsigned ticket counter at float offset 9*GRIDX.
__global__ void __launch_bounds__(256)
dice_fused_kernel(const float* __restrict__ x, const float* __restrict__ t,
                  float* __restrict__ partial, unsigned* __restrict__ ticket,
                  float* __restrict__ out) {
    __shared__ __align__(16) float lx[WPB][CHUNK];
    __shared__ __align__(16) float lt[WPB][CHUNK];
    __shared__ float red[3][WPB];
    __shared__ float fin[9][WPB];
    __shared__ unsigned last_flag;

    const int lane = threadIdx.x & 63;
    const int wave = threadIdx.x >> 6;
    const int ch = blockIdx.y;
    const int gwx = blockIdx.x * WPB + wave;
    const size_t ch_base = (size_t)ch * PER_CH;

    float* lxw = &lx[wave][0];
    float* ltw = &lt[wave][0];

    float sxt = 0.f, sxx = 0.f, stt = 0.f;

#pragma unroll 1
    for (int j = 0; j < CHUNKS_PER_WAVE; ++j) {
        const size_t gbase = ch_base + (size_t)(gwx + j * NWX) * CHUNK;
        const float* gx = x + gbase + lane * 4;   // lane*16 bytes
        const float* gt = t + gbase + lane * 4;
        gload16(gx,       lxw);
        gload16(gx + 256, lxw + 256);
        gload16(gt,       ltw);
        gload16(gt + 256, ltw + 256);
        asm volatile("s_waitcnt vmcnt(0)" ::: "memory");

        float4 x0 = *reinterpret_cast<const float4*>(lxw + lane * 4);
        float4 x1 = *reinterpret_cast<const float4*>(lxw + 256 + lane * 4);
        float4 t0 = *reinterpret_cast<const float4*>(ltw + lane * 4);
        float4 t1 = *reinterpret_cast<const float4*>(ltw + 256 + lane * 4);

        sxt += x0.x * t0.x + x0.y * t0.y + x0.z * t0.z + x0.w * t0.w
             + x1.x * t1.x + x1.y * t1.y + x1.z * t1.z + x1.w * t1.w;
        sxx += x0.x * x0.x + x0.y * x0.y + x0.z * x0.z + x0.w * x0.w
             + x1.x * x1.x + x1.y * x1.y + x1.z * x1.z + x1.w * x1.w;
        stt += t0.x * t0.x + t0.y * t0.y + t0.z * t0.z + t0.w * t0.w
             + t1.x * t1.x + t1.y * t1.y + t1.z * t1.z + t1.w * t1.w;
    }

    // Wave-64 butterfly reduction
    for (int off = 32; off > 0; off >>= 1) {
        sxt += __shfl_xor(sxt, off, 64);
        sxx += __shfl_xor(sxx, off, 64);
        stt += __shfl_xor(stt, off, 64);
    }

    // Cross-wave reduction (4 waves), contention-free partial stores,
    // then the ticket.
    if (lane == 0) {
        red[0][wave] = sxt;
        red[1][wave] = sxx;
        red[2][wave] = stt;
    }
    __syncthreads();
    if (threadIdx.x == 0) {
        float bxt = red[0][0] + red[0][1] + red[0][2] + red[0][3];
        float bxx = red[1][0] + red[1][1] + red[1][2] + red[1][3];
        float btt = red[2][0] + red[2][1] + red[2][2] + red[2][3];
        partial[(ch * 3 + 0) * GRIDX + blockIdx.x] = bxt;
        partial[(ch * 3 + 1) * GRIDX + blockIdx.x] = bxx;
        partial[(ch * 3 + 2) * GRIDX + blockIdx.x] = btt;
        __threadfence();                          // publish partials
        unsigned old = atomicAdd(ticket, 1u);     // device-scope
        last_flag = (old == TOTAL_BLOCKS - 1) ? 1u : 0u;
    }
    __syncthreads();

    // Last-arriving block reduces all partials and writes the loss.
    if (last_flag) {
        __threadfence();                          // acquire: see all partials
        float s[9];
#pragma unroll
        for (int r = 0; r < 9; ++r)
            s[r] = partial[r * GRIDX + threadIdx.x]
                 + partial[r * GRIDX + threadIdx.x + 256];
        for (int off = 32; off > 0; off >>= 1) {
#pragma unroll
            for (int r = 0; r < 9; ++r) s[r] += __shfl_xor(s[r], off, 64);
        }
        if (lane == 0) {
#pragma unroll
            for (int r = 0; r < 9; ++r) fin[r][wave] = s[r];
        }
        __syncthreads();
        if (threadIdx.x == 0) {
            float loss = 0.f;
#pragma unroll
            for (int c = 0; c < NCH; ++c) {
                float num = fin[c * 3 + 0][0] + fin[c * 3 + 0][1]
                          + fin[c * 3 + 0][2] + fin[c * 3 + 0][3];
                float sxx_ = fin[c * 3 + 1][0] + fin[c * 3 + 1][1]
                           + fin[c * 3 + 1][2] + fin[c * 3 + 1][3];
                float stt_ = fin[c * 3 + 2][0] + fin[c * 3 + 2][1]
                           + fin[c * 3 + 2][2] + fin[c * 3 + 2][3];
                loss += -2.f * (num / fmaxf(sxx_ + stt_, EPS));
            }
            out[0] = loss;
        }
    }
}

extern "C" void kernel_launch(void* const* d_in, const int* in_sizes, int n_in,
                              void* d_out, int out_size, void* d_ws, size_t ws_size,
                              hipStream_t stream) {
    const float* x = (const float*)d_in[0];
    const float* t = (const float*)d_in[1];
    float* partial = (float*)d_ws;                       // 9*GRIDX floats
    unsigned* ticket = (unsigned*)(partial + 9 * GRIDX); // 4 bytes
    float* out = (float*)d_out;

    // Ticket must start at 0 every call (ws is poisoned once, not restored).
    hipMemsetAsync(ticket, 0, sizeof(unsigned), stream);

    dim3 grid(GRIDX, NCH);
    dice_fused_kernel<<<grid, THREADS, 0, stream>>>(x, t, partial, ticket, out);
}

// Round 8
// 30.222 us; speedup vs baseline: 2.6813x; 2.6813x over previous
//
#include <hip/hip_runtime.h>

// Channelwise Sorensen-Dice over (1,3,96,256,256) fp32; each channel is a
// contiguous 6,291,456-float block. Per-channel sum(x*t), sum(x*x), sum(t*t);
// loss = sum_c -2*num/max(den,eps).
//
// R8: R5's two-kernel structure (contention-free partials; no cross-XCD
// fencing — R7 proved that costs ~75us). Single variable vs R5: smaller
// chunks (256 floats) + 2x grid -> 8 resident blocks/CU = 32 waves/CU
// (was 6 blocks/24 waves), testing whether wave-occupancy is the last
// limiter on the streaming rate.
#define NCH 3
#define PER_CH 6291456
#define THREADS 256
#define WPB 4                       // waves per block
#define GRIDX 1024                  // blocks per channel
#define NWX (GRIDX * WPB)           // 4096 waves per channel
#define CHUNK 256                   // floats per array per chunk = 1 KB = one gload16
#define CHUNKS_PER_WAVE 6           // PER_CH / (CHUNK * NWX) == 6 exactly
#define EPS 1e-6f

__device__ __forceinline__ void gload16(const float* g, float* l) {
    // dwordx4 direct global->LDS: lane i's 16B land at l + i*16.
    __builtin_amdgcn_global_load_lds(
        (__attribute__((address_space(1))) void*)g,
        (__attribute__((address_space(3))) void*)l,
        16, 0, 0);
}

// partial layout in d_ws: partial[(ch*3+k)*GRIDX + bx], k=0:xt 1:xx 2:tt
__global__ void __launch_bounds__(256)
dice_partial_kernel(const float* __restrict__ x, const float* __restrict__ t,
                    float* __restrict__ partial) {
    __shared__ __align__(16) float lx[WPB][CHUNK];
    __shared__ __align__(16) float lt[WPB][CHUNK];
    __shared__ float red[3][WPB];

    const int lane = threadIdx.x & 63;
    const int wave = threadIdx.x >> 6;
    const int ch = blockIdx.y;
    const int gwx = blockIdx.x * WPB + wave;
    const size_t ch_base = (size_t)ch * PER_CH + (size_t)lane * 4;

    float* lxw = &lx[wave][0];
    float* ltw = &lt[wave][0];

    float sxt = 0.f, sxx = 0.f, stt = 0.f;

#pragma unroll 1
    for (int j = 0; j < CHUNKS_PER_WAVE; ++j) {
        const size_t gbase = ch_base + (size_t)(gwx + j * NWX) * CHUNK;
        gload16(x + gbase, lxw);
        gload16(t + gbase, ltw);
        asm volatile("s_waitcnt vmcnt(0)" ::: "memory");

        float4 xv = *reinterpret_cast<const float4*>(lxw + lane * 4);
        float4 tv = *reinterpret_cast<const float4*>(ltw + lane * 4);

        sxt += xv.x * tv.x + xv.y * tv.y + xv.z * tv.z + xv.w * tv.w;
        sxx += xv.x * xv.x + xv.y * xv.y + xv.z * xv.z + xv.w * xv.w;
        stt += tv.x * tv.x + tv.y * tv.y + tv.z * tv.z + tv.w * tv.w;
    }

    // Wave-64 butterfly reduction
    for (int off = 32; off > 0; off >>= 1) {
        sxt += __shfl_xor(sxt, off, 64);
        sxx += __shfl_xor(sxx, off, 64);
        stt += __shfl_xor(stt, off, 64);
    }

    // Cross-wave reduction (4 waves), then contention-free plain stores.
    if (lane == 0) {
        red[0][wave] = sxt;
        red[1][wave] = sxx;
        red[2][wave] = stt;
    }
    __syncthreads();
    if (threadIdx.x == 0) {
        float bxt = red[0][0] + red[0][1] + red[0][2] + red[0][3];
        float bxx = red[1][0] + red[1][1] + red[1][2] + red[1][3];
        float btt = red[2][0] + red[2][1] + red[2][2] + red[2][3];
        partial[(ch * 3 + 0) * GRIDX + blockIdx.x] = bxt;
        partial[(ch * 3 + 1) * GRIDX + blockIdx.x] = bxx;
        partial[(ch * 3 + 2) * GRIDX + blockIdx.x] = btt;
    }
}

// 9 waves (576 threads): wave w reduces row w of partial[9][GRIDX].
__global__ void __launch_bounds__(576)
dice_final_kernel(const float* __restrict__ partial, float* __restrict__ out) {
    __shared__ float red[9];
    const int w = threadIdx.x >> 6;     // 0..8
    const int lane = threadIdx.x & 63;

    float s = 0.f;
    const float* row = partial + w * GRIDX;
#pragma unroll
    for (int i = 0; i < GRIDX / 64; ++i) s += row[lane + i * 64];
    for (int off = 32; off > 0; off >>= 1) s += __shfl_xor(s, off, 64);
    if (lane == 0) red[w] = s;
    __syncthreads();

    if (threadIdx.x == 0) {
        float loss = 0.f;
        for (int c = 0; c < NCH; ++c) {
            float num = red[c * 3 + 0];
            float den = red[c * 3 + 1] + red[c * 3 + 2];
            loss += -2.f * (num / fmaxf(den, EPS));
        }
        out[0] = loss;
    }
}

extern "C" void kernel_launch(void* const* d_in, const int* in_sizes, int n_in,
                              void* d_out, int out_size, void* d_ws, size_t ws_size,
                              hipStream_t stream) {
    const float* x = (const float*)d_in[0];
    const float* t = (const float*)d_in[1];
    float* partial = (float*)d_ws;      // 9*GRIDX floats = 36 KB, fully overwritten each call
    float* out = (float*)d_out;

    dim3 grid(GRIDX, NCH);
    dice_partial_kernel<<<grid, THREADS, 0, stream>>>(x, t, partial);
    dice_final_kernel<<<1, 576, 0, stream>>>(partial, out);
}

// Round 9
// 29.511 us; speedup vs baseline: 2.7459x; 1.0241x over previous
//
#include <hip/hip_runtime.h>

// Channelwise Sorensen-Dice over (1,3,96,256,256) fp32; each channel is a
// contiguous 6,291,456-float block. Per-channel sum(x*t), sum(x*x), sum(t*t);
// loss = sum_c -2*num/max(den,eps).
//
// FINAL (= R5, best measured 29.46 us):
//  - Stage 1: 1536 blocks stream x,t via global_load_lds (dwordx4, 1 KB/wave
//    per instr) into wave-private LDS chunks (2 KB per array), reduce to 3
//    per-block partial sums, store to DISTINCT slots (no atomics -- R1-R4
//    showed same-line atomicAdds serialized the whole kernel at ~10ns each).
//  - Stage 2: tiny 9-wave kernel reduces partial[9][512] and writes the loss.
//  - Measured 5.9 TB/s effective streaming = 94% of the m13 per-CU request
//    ceiling; R6 (deeper vmcnt pipeline) and R8 (32 waves/CU) both neutral ->
//    request-rate bound. R7 (fused finalize via threadfence ticket) cost
//    +52 us in cross-XCD coherence -- dependent launch is cheaper.
#define NCH 3
#define PER_CH 6291456
#define THREADS 256
#define WPB 4                       // waves per block
#define GRIDX 512                   // blocks per channel
#define NWX (GRIDX * WPB)           // 2048 waves per channel
#define CHUNK 512                   // floats per array per chunk (2 KB)
#define CHUNKS_PER_WAVE 6           // PER_CH / CHUNK / NWX == 6 exactly
#define EPS 1e-6f

__device__ __forceinline__ void gload16(const float* g, float* l) {
    // dwordx4 direct global->LDS: lane i's 16B land at l + i*16.
    __builtin_amdgcn_global_load_lds(
        (__attribute__((address_space(1))) void*)g,
        (__attribute__((address_space(3))) void*)l,
        16, 0, 0);
}

// partial layout in d_ws: partial[(ch*3+k)*GRIDX + bx], k=0:xt 1:xx 2:tt
__global__ void __launch_bounds__(256)
dice_partial_kernel(const float* __restrict__ x, const float* __restrict__ t,
                    float* __restrict__ partial) {
    __shared__ __align__(16) float lx[WPB][CHUNK];
    __shared__ __align__(16) float lt[WPB][CHUNK];
    __shared__ float red[3][WPB];

    const int lane = threadIdx.x & 63;
    const int wave = threadIdx.x >> 6;
    const int ch = blockIdx.y;
    const int gwx = blockIdx.x * WPB + wave;
    const size_t ch_base = (size_t)ch * PER_CH;

    float* lxw = &lx[wave][0];
    float* ltw = &lt[wave][0];

    float sxt = 0.f, sxx = 0.f, stt = 0.f;

#pragma unroll 1
    for (int j = 0; j < CHUNKS_PER_WAVE; ++j) {
        const size_t gbase = ch_base + (size_t)(gwx + j * NWX) * CHUNK;
        const float* gx = x + gbase + lane * 4;   // lane*16 bytes
        const float* gt = t + gbase + lane * 4;
        gload16(gx,       lxw);         // floats [0,256)
        gload16(gx + 256, lxw + 256);   // floats [256,512)
        gload16(gt,       ltw);
        gload16(gt + 256, ltw + 256);
        asm volatile("s_waitcnt vmcnt(0)" ::: "memory");

        float4 x0 = *reinterpret_cast<const float4*>(lxw + lane * 4);
        float4 x1 = *reinterpret_cast<const float4*>(lxw + 256 + lane * 4);
        float4 t0 = *reinterpret_cast<const float4*>(ltw + lane * 4);
        float4 t1 = *reinterpret_cast<const float4*>(ltw + 256 + lane * 4);

        sxt += x0.x * t0.x + x0.y * t0.y + x0.z * t0.z + x0.w * t0.w
             + x1.x * t1.x + x1.y * t1.y + x1.z * t1.z + x1.w * t1.w;
        sxx += x0.x * x0.x + x0.y * x0.y + x0.z * x0.z + x0.w * x0.w
             + x1.x * x1.x + x1.y * x1.y + x1.z * x1.z + x1.w * x1.w;
        stt += t0.x * t0.x + t0.y * t0.y + t0.z * t0.z + t0.w * t0.w
             + t1.x * t1.x + t1.y * t1.y + t1.z * t1.z + t1.w * t1.w;
    }

    // Wave-64 butterfly reduction
    for (int off = 32; off > 0; off >>= 1) {
        sxt += __shfl_xor(sxt, off, 64);
        sxx += __shfl_xor(sxx, off, 64);
        stt += __shfl_xor(stt, off, 64);
    }

    // Cross-wave reduction (4 waves), then contention-free plain stores.
    if (lane == 0) {
        red[0][wave] = sxt;
        red[1][wave] = sxx;
        red[2][wave] = stt;
    }
    __syncthreads();
    if (threadIdx.x == 0) {
        float bxt = red[0][0] + red[0][1] + red[0][2] + red[0][3];
        float bxx = red[1][0] + red[1][1] + red[1][2] + red[1][3];
        float btt = red[2][0] + red[2][1] + red[2][2] + red[2][3];
        partial[(ch * 3 + 0) * GRIDX + blockIdx.x] = bxt;
        partial[(ch * 3 + 1) * GRIDX + blockIdx.x] = bxx;
        partial[(ch * 3 + 2) * GRIDX + blockIdx.x] = btt;
    }
}

// 9 waves (576 threads): wave w reduces row w of partial[9][GRIDX].
__global__ void __launch_bounds__(576)
dice_final_kernel(const float* __restrict__ partial, float* __restrict__ out) {
    __shared__ float red[9];
    const int w = threadIdx.x >> 6;     // 0..8
    const int lane = threadIdx.x & 63;

    float s = 0.f;
    const float* row = partial + w * GRIDX;
#pragma unroll
    for (int i = 0; i < GRIDX / 64; ++i) s += row[lane + i * 64];
    for (int off = 32; off > 0; off >>= 1) s += __shfl_xor(s, off, 64);
    if (lane == 0) red[w] = s;
    __syncthreads();

    if (threadIdx.x == 0) {
        float loss = 0.f;
        for (int c = 0; c < NCH; ++c) {
            float num = red[c * 3 + 0];
            float den = red[c * 3 + 1] + red[c * 3 + 2];
            loss += -2.f * (num / fmaxf(den, EPS));
        }
        out[0] = loss;
    }
}

extern "C" void kernel_launch(void* const* d_in, const int* in_sizes, int n_in,
                              void* d_out, int out_size, void* d_ws, size_t ws_size,
                              hipStream_t stream) {
    const float* x = (const float*)d_in[0];
    const float* t = (const float*)d_in[1];
    float* partial = (float*)d_ws;      // 9*GRIDX floats = 18 KB, fully overwritten each call
    float* out = (float*)d_out;

    dim3 grid(GRIDX, NCH);
    dice_partial_kernel<<<grid, THREADS, 0, stream>>>(x, t, partial);
    dice_final_kernel<<<1, 576, 0, stream>>>(partial, out);
}